// Round 5
// baseline (840.764 us; speedup 1.0000x reference)
//
// CrossAttentionBlock_56813827392085 — fused transformer block, bf16 MFMA internals. R5:
//  - transposed MFMA (acc[nt][mt] = mfma(Wfrag, Xfrag)): lane holds 4 consecutive out-cols
//    -> vector epilogue (ushort4/float4) instead of 64 scalar stores (the flat ~46us VALU)
//  - BK=32 K-loop restored (R4's BK=64: same busy time, +27us idle from occupancy drop)
//  - keeps: R4 dispatch merges, fused dinv in apply, zero-conflict LDS swizzle, fast gelu
#include <hip/hip_runtime.h>
#include <hip/hip_bf16.h>
#include <math.h>
#include <stdint.h>

typedef unsigned short u16;
typedef __attribute__((ext_vector_type(8))) short bh8;
typedef __attribute__((ext_vector_type(4))) float fx4;

#define DEV static __device__ __forceinline__

DEV float bf2f(u16 u){ union{unsigned u; float f;} v; v.u = ((unsigned)u)<<16; return v.f; }
DEV u16 f2bf(float f){ union{float f; unsigned u;} v; v.f = f;
  return (u16)((v.u + 0x7fffu + ((v.u>>16)&1u))>>16); }               // RNE

DEV void async16(const u16* g, u16* l){
  __builtin_amdgcn_global_load_lds((__attribute__((address_space(1))) void*)(uintptr_t)g,
                                   (__attribute__((address_space(3))) void*)l, 16, 0, 0);
}

DEV float gelu_fast(float x){
  float u = 0.7978845608f*(x + 0.044715f*x*x*x);
  float e = __expf(-2.f*fabsf(u));
  float t = __fdividef(1.f - e, 1.f + e);
  t = copysignf(t, u);
  return 0.5f*x*(1.f + t);
}

// ---------------- weight fp32 -> bf16 pack ----------------
struct WDesc { const float* src[14]; int off[14]; };
__global__ __launch_bounds__(256) void convw_kernel(WDesc d, u16* __restrict__ dst){
  int i = blockIdx.x*256 + threadIdx.x;
  int s = 0;
  #pragma unroll
  for(int j=1;j<14;j++) if(i >= d.off[j]) s = j;
  dst[i] = f2bf(d.src[s][i - d.off[s]]);
}

// ---------------- LayerNorm (C=512), fp32 in -> bf16 out ----------------
DEV float wsum64(float s){
  s += __shfl_xor(s,1,64);  s += __shfl_xor(s,2,64);  s += __shfl_xor(s,4,64);
  s += __shfl_xor(s,8,64);  s += __shfl_xor(s,16,64); s += __shfl_xor(s,32,64);
  return s;
}
DEV void ln_row(const float* xrow, const float* g, const float* bta, u16* orow, int lane){
  const float4* xr = (const float4*)xrow + lane*2;
  float4 a = xr[0], c = xr[1];
  float s = a.x+a.y+a.z+a.w + c.x+c.y+c.z+c.w;
  float mean = wsum64(s) * (1.f/512.f);
  float d0=a.x-mean,d1=a.y-mean,d2=a.z-mean,d3=a.w-mean;
  float d4=c.x-mean,d5=c.y-mean,d6=c.z-mean,d7=c.w-mean;
  float sv = d0*d0+d1*d1+d2*d2+d3*d3+d4*d4+d5*d5+d6*d6+d7*d7;
  float rstd = rsqrtf(wsum64(sv)*(1.f/512.f) + 1e-5f);
  const float4* gr = (const float4*)g   + lane*2;
  const float4* br = (const float4*)bta + lane*2;
  float4 g0=gr[0], g1=gr[1], b0=br[0], b1=br[1];
  bh8 o;
  o[0]=(short)f2bf(d0*rstd*g0.x+b0.x); o[1]=(short)f2bf(d1*rstd*g0.y+b0.y);
  o[2]=(short)f2bf(d2*rstd*g0.z+b0.z); o[3]=(short)f2bf(d3*rstd*g0.w+b0.w);
  o[4]=(short)f2bf(d4*rstd*g1.x+b1.x); o[5]=(short)f2bf(d5*rstd*g1.y+b1.y);
  o[6]=(short)f2bf(d6*rstd*g1.z+b1.z); o[7]=(short)f2bf(d7*rstd*g1.w+b1.w);
  *(bh8*)(orow + lane*8) = o;
}
__global__ __launch_bounds__(256) void ln_kernel(const float* __restrict__ x,
    const float* __restrict__ g, const float* __restrict__ bta, u16* __restrict__ out){
  int row  = blockIdx.x*4 + (threadIdx.x>>6);
  ln_row(x + (size_t)row*512, g, bta, out + (size_t)row*512, threadIdx.x&63);
}
__global__ __launch_bounds__(256) void lny_kernel(const float* __restrict__ ys,
    const float* __restrict__ g2, const float* __restrict__ b2, u16* __restrict__ out){
  int row  = blockIdx.x*4 + (threadIdx.x>>6);
  int i = row>>14;
  ln_row(ys + (size_t)row*512, g2 + i*512, b2 + i*512, out + (size_t)row*512, threadIdx.x&63);
}

// ---- shared GEMM K-loop: 128x128 tile, BK=32, swizzled LDS (conflict-free, R3-proven) ----
// TRANSPOSED accumulate: acc[nt][mt] = mfma(Wfrag, Xfrag) -> D row-index = out COLUMN.
// C/D map: out_row = tile_m + l15, out_col = tile_n + quad*4 + r  (4 consecutive cols/lane)
#define GEMM_KLOOP(Ab, Wb, K)                                                        \
  const int srow = w*32 + (lane>>2);                                                 \
  const int scol = (((lane&3) ^ ((srow>>1)&3)) * 8);                                 \
  const int rsw  = ((l15>>1)&3) ^ quad;                                              \
  for(int k0=0;k0<K;k0+=32){                                                         \
    __syncthreads();                                                                 \
    async16(Ab + (size_t)srow*K      + k0 + scol, &lsA[(w*32   )*32]);               \
    async16(Ab + (size_t)(srow+16)*K + k0 + scol, &lsA[(w*32+16)*32]);               \
    async16(Wb + (size_t)srow*K      + k0 + scol, &lsB[(w*32   )*32]);               \
    async16(Wb + (size_t)(srow+16)*K + k0 + scol, &lsB[(w*32+16)*32]);               \
    __syncthreads();                                                                 \
    bh8 af[4], bfx[4];                                                               \
    _Pragma("unroll")                                                                \
    for(int t=0;t<4;t++){                                                            \
      af[t]  = *(const bh8*)&lsA[(wm*64+t*16+l15)*32 + rsw*8];                       \
      bfx[t] = *(const bh8*)&lsB[(wn*64+t*16+l15)*32 + rsw*8];                       \
    }                                                                                \
    _Pragma("unroll")                                                                \
    for(int nt=0;nt<4;nt++)                                                          \
      _Pragma("unroll")                                                              \
      for(int mt=0;mt<4;mt++)                                                        \
        acc[nt][mt] = __builtin_amdgcn_mfma_f32_16x16x32_bf16(bfx[nt], af[mt], acc[nt][mt], 0,0,0); \
  }

// ---------------- multi-output projection GEMM: C_sub = A * W_sub^T + bias ----------------
struct SubD { const float* bias; u16* out; float* ksum; int mode; };
struct Subs3 { SubD s[3]; };
__global__ __launch_bounds__(256) void gemm_qkv(const u16* __restrict__ A,
    const u16* __restrict__ W, Subs3 subs, int K, int wstride, int bstride, int ksstride){
  __shared__ __align__(16) u16 lsA[128*32];
  __shared__ __align__(16) u16 lsB[128*32];
  const int tid = threadIdx.x, lane = tid&63, w = tid>>6;
  const int quad = lane>>4, l15 = lane&15;
  const int bn = blockIdx.x, bm = blockIdx.y;
  const int iset = bm>>7;
  const int wm = w&1, wn = w>>1;
  fx4 acc[4][4];
  #pragma unroll
  for(int i=0;i<4;i++)
    #pragma unroll
    for(int j=0;j<4;j++) acc[i][j] = (fx4){0.f,0.f,0.f,0.f};
  const u16* Ab = A + (size_t)bm*128*K;
  const u16* Wb = W + (size_t)iset*wstride + (size_t)bn*128*K;
  GEMM_KLOOP(Ab, Wb, K)
  const SubD sub = subs.s[bn>>2];
  const int colw = (bn&3)*128 + wn*64;
  const float* bias = sub.bias + iset*bstride;
  float bb[4][4];
  #pragma unroll
  for(int nt=0;nt<4;nt++){
    float4 b4 = *(const float4*)&bias[colw + nt*16 + quad*4];
    bb[nt][0]=b4.x; bb[nt][1]=b4.y; bb[nt][2]=b4.z; bb[nt][3]=b4.w;
  }

  if(sub.mode==1){
    float ksacc[4][4];
    #pragma unroll
    for(int nt=0;nt<4;nt++)
      #pragma unroll
      for(int r=0;r<4;r++) ksacc[nt][r]=0.f;
    #pragma unroll
    for(int mt=0;mt<4;mt++){
      int row = bm*128 + wm*64 + mt*16 + l15;
      size_t rb = (size_t)row*512;
      float e[4][4];
      float mx = -3.4e38f;
      #pragma unroll
      for(int nt=0;nt<4;nt++)
        #pragma unroll
        for(int r=0;r<4;r++){ float v = acc[nt][mt][r] + bb[nt][r]; e[nt][r]=v; mx=fmaxf(mx,v); }
      mx = fmaxf(mx, __shfl_xor(mx,16,64)); mx = fmaxf(mx, __shfl_xor(mx,32,64));
      float s = 0.f;
      #pragma unroll
      for(int nt=0;nt<4;nt++)
        #pragma unroll
        for(int r=0;r<4;r++){ e[nt][r]=__expf(e[nt][r]-mx); s += e[nt][r]; }
      s += __shfl_xor(s,16,64); s += __shfl_xor(s,32,64);
      float inv = __fdividef(1.f, s);
      #pragma unroll
      for(int nt=0;nt<4;nt++){
        float e0=e[nt][0]*inv, e1=e[nt][1]*inv, e2=e[nt][2]*inv, e3=e[nt][3]*inv;
        ksacc[nt][0]+=e0; ksacc[nt][1]+=e1; ksacc[nt][2]+=e2; ksacc[nt][3]+=e3;
        ushort4 o = { f2bf(e0), f2bf(e1), f2bf(e2), f2bf(e3) };
        *(ushort4*)&sub.out[rb + colw + nt*16 + quad*4] = o;
      }
    }
    if(sub.ksum){
      int b = (bm&127)>>5;
      float* ks = sub.ksum + iset*ksstride + b*512;
      #pragma unroll
      for(int nt=0;nt<4;nt++)
        #pragma unroll
        for(int r=0;r<4;r++){
          float s = ksacc[nt][r];
          s += __shfl_xor(s,1,64); s += __shfl_xor(s,2,64);
          s += __shfl_xor(s,4,64); s += __shfl_xor(s,8,64);
          if(l15==0) atomicAdd(&ks[colw + nt*16 + quad*4 + r], s);
        }
    }
  } else {
    #pragma unroll
    for(int mt=0;mt<4;mt++){
      int row = bm*128 + wm*64 + mt*16 + l15;
      size_t rb = (size_t)row*512;
      #pragma unroll
      for(int nt=0;nt<4;nt++){
        ushort4 o = { f2bf(acc[nt][mt][0]+bb[nt][0]), f2bf(acc[nt][mt][1]+bb[nt][1]),
                      f2bf(acc[nt][mt][2]+bb[nt][2]), f2bf(acc[nt][mt][3]+bb[nt][3]) };
        *(ushort4*)&sub.out[rb + colw + nt*16 + quad*4] = o;
      }
    }
  }
}

// ---------------- GEMM C = A[MxK] * W[NxK]^T + bias, EPI 2: gelu->bf16, 3: +res->fp32 ----
template<int EPI>
__global__ __launch_bounds__(256) void gemm_bt(const u16* __restrict__ A,
    const u16* __restrict__ W, const float* __restrict__ bias,
    const float* __restrict__ res, void* __restrict__ out, int N, int K){
  __shared__ __align__(16) u16 lsA[128*32];
  __shared__ __align__(16) u16 lsB[128*32];
  const int tid = threadIdx.x, lane = tid&63, w = tid>>6;
  const int quad = lane>>4, l15 = lane&15;
  const int bn = blockIdx.x, bm = blockIdx.y;
  const int wm = w&1, wn = w>>1;
  fx4 acc[4][4];
  #pragma unroll
  for(int i=0;i<4;i++)
    #pragma unroll
    for(int j=0;j<4;j++) acc[i][j] = (fx4){0.f,0.f,0.f,0.f};
  const u16* Ab = A + (size_t)bm*128*K;
  const u16* Wb = W + (size_t)bn*128*K;
  GEMM_KLOOP(Ab, Wb, K)
  const int colbase = bn*128 + wn*64;
  float bb[4][4];
  #pragma unroll
  for(int nt=0;nt<4;nt++){
    float4 b4 = *(const float4*)&bias[colbase + nt*16 + quad*4];
    bb[nt][0]=b4.x; bb[nt][1]=b4.y; bb[nt][2]=b4.z; bb[nt][3]=b4.w;
  }

  if(EPI==3){
    float* of = (float*)out;
    #pragma unroll
    for(int mt=0;mt<4;mt++){
      int row = bm*128 + wm*64 + mt*16 + l15;
      size_t rb = (size_t)row*N;
      #pragma unroll
      for(int nt=0;nt<4;nt++){
        int col = colbase + nt*16 + quad*4;
        float4 rv = *(const float4*)&res[rb + col];
        float4 ov;
        ov.x = rv.x + acc[nt][mt][0] + bb[nt][0];
        ov.y = rv.y + acc[nt][mt][1] + bb[nt][1];
        ov.z = rv.z + acc[nt][mt][2] + bb[nt][2];
        ov.w = rv.w + acc[nt][mt][3] + bb[nt][3];
        *(float4*)&of[rb + col] = ov;
      }
    }
  } else {
    u16* ob = (u16*)out;
    #pragma unroll
    for(int mt=0;mt<4;mt++){
      int row = bm*128 + wm*64 + mt*16 + l15;
      size_t rb = (size_t)row*N;
      #pragma unroll
      for(int nt=0;nt<4;nt++){
        ushort4 o = { f2bf(gelu_fast(acc[nt][mt][0]+bb[nt][0])),
                      f2bf(gelu_fast(acc[nt][mt][1]+bb[nt][1])),
                      f2bf(gelu_fast(acc[nt][mt][2]+bb[nt][2])),
                      f2bf(gelu_fast(acc[nt][mt][3]+bb[nt][3])) };
        *(ushort4*)&ob[rb + colbase + nt*16 + quad*4] = o;
      }
    }
  }
}

// ---------------- ctx[i,b,h][d1][d2] = sum_t k[t][d1] v[t][d2] (MFMA over t) ----------------
__global__ __launch_bounds__(256) void ctx_kernel(const u16* __restrict__ kb,
    const u16* __restrict__ vb, float* __restrict__ ctx, size_t kstride){
  __shared__ __align__(16) u16 lk[64*72];  // transposed [d][t], stride 72
  __shared__ __align__(16) u16 lv[64*72];
  const int tid=threadIdx.x, lane=tid&63, w=tid>>6, quad=lane>>4, l15=lane&15;
  const int bh2 = blockIdx.x, i = bh2>>5, h = bh2&7, b = (bh2>>3)&3;
  const u16* kbase = kb + (size_t)i*kstride;
  const u16* vbase = vb + (size_t)i*kstride;
  const size_t rowbase = (size_t)b*4096 + (size_t)blockIdx.y*512;
  const int mt0=(w&1)*32, nt0=(w>>1)*32;
  fx4 acc[2][2];
  #pragma unroll
  for(int x=0;x<2;x++)
    #pragma unroll
    for(int j=0;j<2;j++) acc[x][j] = (fx4){0.f,0.f,0.f,0.f};
  const int tl = tid>>2, part = tid&3;
  for(int it=0; it<8; it++){
    __syncthreads();
    {
      size_t gro = (rowbase + it*64 + tl)*512 + h*64 + part*16;
      bh8 k0 = *(const bh8*)(kbase + gro); bh8 k1 = *(const bh8*)(kbase + gro + 8);
      bh8 v0 = *(const bh8*)(vbase + gro); bh8 v1 = *(const bh8*)(vbase + gro + 8);
      #pragma unroll
      for(int j=0;j<8;j++){
        lk[(part*16+j  )*72 + tl] = (u16)k0[j];
        lk[(part*16+8+j)*72 + tl] = (u16)k1[j];
        lv[(part*16+j  )*72 + tl] = (u16)v0[j];
        lv[(part*16+8+j)*72 + tl] = (u16)v1[j];
      }
    }
    __syncthreads();
    #pragma unroll
    for(int ks=0;ks<2;ks++){
      bh8 a0 = *(const bh8*)&lk[(mt0    +l15)*72 + ks*32 + quad*8];
      bh8 a1 = *(const bh8*)&lk[(mt0+16 +l15)*72 + ks*32 + quad*8];
      bh8 b0 = *(const bh8*)&lv[(nt0    +l15)*72 + ks*32 + quad*8];
      bh8 b1 = *(const bh8*)&lv[(nt0+16 +l15)*72 + ks*32 + quad*8];
      acc[0][0] = __builtin_amdgcn_mfma_f32_16x16x32_bf16(a0,b0,acc[0][0],0,0,0);
      acc[0][1] = __builtin_amdgcn_mfma_f32_16x16x32_bf16(a0,b1,acc[0][1],0,0,0);
      acc[1][0] = __builtin_amdgcn_mfma_f32_16x16x32_bf16(a1,b0,acc[1][0],0,0,0);
      acc[1][1] = __builtin_amdgcn_mfma_f32_16x16x32_bf16(a1,b1,acc[1][1],0,0,0);
    }
  }
  float* cb = ctx + (size_t)bh2*4096;
  #pragma unroll
  for(int mi=0;mi<2;mi++)
    #pragma unroll
    for(int ni=0;ni<2;ni++)
      #pragma unroll
      for(int r=0;r<4;r++){
        int d1 = mt0 + mi*16 + quad*4 + r;
        int d2 = nt0 + ni*16 + l15;
        atomicAdd(&cb[d1*64 + d2], acc[mi][ni][r]);
      }
}

// ------- out = q + sum_i (q @ ctx_i) * Dinv_i, Dinv fused (quad-shuffle over q frags) -------
template<int NIN>
__global__ __launch_bounds__(256) void apply_kernel(const u16* __restrict__ q,
    const float* __restrict__ ctx, const float* __restrict__ ksum, float eps,
    u16* __restrict__ out){
  __shared__ __align__(16) u16 lctx[(NIN+1)*64*72];
  const int tid=threadIdx.x, lane=tid&63, w=tid>>6, quad=lane>>4, l15=lane&15;
  const int bh = blockIdx.x, b=bh>>3, h=bh&7;
  {
    int base = tid*16;
    int d1 = base>>6, d2b = base&63;
    #pragma unroll
    for(int s=0;s<=NIN;s++){
      u16* dst = &lctx[s*64*72];
      if(s<NIN){
        const float* sp = ctx + ((size_t)s*32 + bh)*4096 + base;
        #pragma unroll
        for(int j=0;j<16;j++) dst[(d2b+j)*72 + d1] = f2bf(sp[j]);
      } else {
        #pragma unroll
        for(int j=0;j<16;j++) dst[(d2b+j)*72 + d1] = ((d2b+j)==d1) ? (u16)0x3f80 : (u16)0;
      }
    }
  }
  float kslo[NIN][8], kshi[NIN][8];
  #pragma unroll
  for(int s=0;s<NIN;s++){
    const float* ks = ksum + s*2048 + b*512 + h*64;
    #pragma unroll
    for(int j=0;j<8;j++){ kslo[s][j] = ks[quad*8+j]; kshi[s][j] = ks[32+quad*8+j]; }
  }
  __syncthreads();
  bh8 bfr[NIN+1][4][2];
  #pragma unroll
  for(int s=0;s<=NIN;s++)
    #pragma unroll
    for(int nt=0;nt<4;nt++)
      #pragma unroll
      for(int ks=0;ks<2;ks++)
        bfr[s][nt][ks] = *(const bh8*)&lctx[s*64*72 + (nt*16+l15)*72 + ks*32 + quad*8];
  const size_t tb0 = (size_t)b*4096 + (size_t)blockIdx.y*256 + w*64;
  for(int g=0;g<4;g++){
    size_t tb = tb0 + g*16;
    const u16* qr = q + (tb + l15)*512 + h*64;
    bh8 a0 = *(const bh8*)(qr + quad*8);
    bh8 a1 = *(const bh8*)(qr + 32 + quad*8);
    float dv[NIN][4];
    #pragma unroll
    for(int s=0;s<NIN;s++){
      float part = 0.f;
      #pragma unroll
      for(int j=0;j<8;j++)
        part += bf2f((u16)a0[j])*kslo[s][j] + bf2f((u16)a1[j])*kshi[s][j];
      part += __shfl_xor(part,16,64); part += __shfl_xor(part,32,64);
      #pragma unroll
      for(int r=0;r<4;r++)
        dv[s][r] = __fdividef(1.f, __shfl(part, quad*4+r, 64) + eps);
    }
    fx4 outv[4];
    #pragma unroll
    for(int nt=0;nt<4;nt++) outv[nt] = (fx4){0.f,0.f,0.f,0.f};
    #pragma unroll
    for(int s=0;s<=NIN;s++){
      fx4 c[4];
      #pragma unroll
      for(int nt=0;nt<4;nt++){
        c[nt] = (fx4){0.f,0.f,0.f,0.f};
        c[nt] = __builtin_amdgcn_mfma_f32_16x16x32_bf16(a0, bfr[s][nt][0], c[nt], 0,0,0);
        c[nt] = __builtin_amdgcn_mfma_f32_16x16x32_bf16(a1, bfr[s][nt][1], c[nt], 0,0,0);
      }
      #pragma unroll
      for(int nt=0;nt<4;nt++)
        #pragma unroll
        for(int r=0;r<4;r++) outv[nt][r] += c[nt][r]*((s==NIN)?1.f:dv[s][r]);
    }
    #pragma unroll
    for(int nt=0;nt<4;nt++)
      #pragma unroll
      for(int r=0;r<4;r++)
        out[(tb+quad*4+r)*512 + h*64 + nt*16 + l15] = f2bf(outv[nt][r]);
  }
}

// =========================================================================
extern "C" void kernel_launch(void* const* d_in, const int* in_sizes, int n_in,
                              void* d_out, int out_size, void* d_ws, size_t ws_size,
                              hipStream_t stream){
  const float* x_in =(const float*)d_in[0];
  const float* ys   =(const float*)d_in[1];
  const float* ln1g =(const float*)d_in[2],  *ln1b=(const float*)d_in[3];
  const float* ln2g =(const float*)d_in[4],  *ln2b=(const float*)d_in[5];
  const float* ln3g =(const float*)d_in[6],  *ln3b=(const float*)d_in[7];
  const float* ln4g =(const float*)d_in[8],  *ln4b=(const float*)d_in[9];
  const float* ln5g =(const float*)d_in[10], *ln5b=(const float*)d_in[11];
  const float* ca_wq=(const float*)d_in[12], *ca_bq=(const float*)d_in[13];
  const float* ca_wk=(const float*)d_in[14], *ca_bk=(const float*)d_in[15];
  const float* ca_wv=(const float*)d_in[16], *ca_bv=(const float*)d_in[17];
  const float* ca_wo=(const float*)d_in[18], *ca_bo=(const float*)d_in[19];
  const float* sa_wq=(const float*)d_in[20], *sa_bq=(const float*)d_in[21];
  const float* sa_wk=(const float*)d_in[22], *sa_bk=(const float*)d_in[23];
  const float* sa_wv=(const float*)d_in[24], *sa_bv=(const float*)d_in[25];
  const float* sa_wo=(const float*)d_in[26], *sa_bo=(const float*)d_in[27];
  const float* f1w1 =(const float*)d_in[28], *f1b1=(const float*)d_in[29];
  const float* f1w2 =(const float*)d_in[30], *f1b2=(const float*)d_in[31];
  const float* f2w1 =(const float*)d_in[32], *f2b1=(const float*)d_in[33];
  const float* f2w2 =(const float*)d_in[34], *f2b2=(const float*)d_in[35];

  char* p = (char*)d_ws;
  u16*   WBF = (u16*)p;    p += 13631488;   // bf16 weights
  float* XW  = (float*)p;  p += 33554432;   // residual stream fp32 [16384,512]
  u16*   XN2 = (u16*)p;    p += 33554432;   // LN out, up to 2x16384 rows
  u16*   QB  = (u16*)p;    p += 16777216;
  u16*   R1  = (u16*)p;    p += 67108864;   // FFN hidden [16384,2048] OR stacked KB2|VB2
  u16*   OUTB= (u16*)p;    p += 16777216;   // attention output
  float* SM  = (float*)p;  p += 1597440;    // ctx + ksum (zeroed)
  u16*   XN  = XN2;
  u16*   KB2 = R1;
  u16*   VB2 = R1 + 16777216;
  u16*   HB  = R1;
  float* CTXC = SM;                          // [2][32][4096]
  float* CTXS = SM + 262144;                 // [32][4096]
  float* KSC  = SM + 393216;                 // [2][4][512]
  float* KSS  = SM + 397312;                 // [4][512]

  WDesc wd;
  const float* wsrc[14] = {ca_wq, ca_wk, ca_wv, ca_wk+262144, ca_wv+262144, ca_wo,
                           sa_wq, sa_wk, sa_wv, sa_wo, f1w1, f1w2, f2w1, f2w2};
  const int    woff[14] = {0, 262144, 524288, 786432, 1048576, 1310720,
                           1572864, 1835008, 2097152, 2359296,
                           2621440, 3670016, 4718592, 5767168};
  for(int i=0;i<14;i++){ wd.src[i]=wsrc[i]; wd.off[i]=woff[i]; }
  convw_kernel<<<26624,256,0,stream>>>(wd, WBF);
  hipMemsetAsync(SM, 0, 399360*sizeof(float), stream);

  SubD zsub = {nullptr,nullptr,nullptr,0};

  // ---- cross attention ----
  ln_kernel<<<4096,256,0,stream>>>(x_in, ln1g, ln1b, XN);
  { Subs3 s = {{ {ca_bq, QB, nullptr, 1}, zsub, zsub }};
    gemm_qkv<<<dim3(4,128),256,0,stream>>>(XN, WBF+0, s, 512, 0,0,0); }
  lny_kernel<<<8192,256,0,stream>>>(ys, ln2g, ln2b, XN2);   // both ys LNs
  { Subs3 s = {{ {ca_bk, KB2, KSC, 1}, {ca_bv, VB2, nullptr, 0}, zsub }};
    gemm_qkv<<<dim3(8,256),256,0,stream>>>(XN2, WBF+262144, s, 512,
                                           524288, 512, 2048); }  // i = bm>>7
  ctx_kernel<<<dim3(64,8),256,0,stream>>>(KB2, VB2, CTXC, (size_t)16384*512);
  apply_kernel<2><<<dim3(32,16),256,0,stream>>>(QB, CTXC, KSC, 1e-8f, OUTB);
  gemm_bt<3><<<dim3(4,128),256,0,stream>>>(OUTB, WBF+1310720, ca_bo, x_in, XW, 512, 512);

  // ---- FFN 1 ----
  ln_kernel<<<4096,256,0,stream>>>(XW, ln3g, ln3b, XN);
  gemm_bt<2><<<dim3(16,128),256,0,stream>>>(XN, WBF+2621440, f1b1, nullptr, HB, 2048, 512);
  gemm_bt<3><<<dim3(4,128),256,0,stream>>>(HB, WBF+3670016, f1b2, XW, XW, 512, 2048);

  // ---- linear self attention ----
  ln_kernel<<<4096,256,0,stream>>>(XW, ln4g, ln4b, XN);
  { Subs3 s = {{ {sa_bq, QB, nullptr, 1}, {sa_bk, KB2, KSS, 1}, {sa_bv, VB2, nullptr, 0} }};
    gemm_qkv<<<dim3(12,128),256,0,stream>>>(XN, WBF+1572864, s, 512, 0,0,0); }
  ctx_kernel<<<dim3(32,8),256,0,stream>>>(KB2, VB2, CTXS, 0);
  apply_kernel<1><<<dim3(32,16),256,0,stream>>>(QB, CTXS, KSS, 0.f, OUTB);
  gemm_bt<3><<<dim3(4,128),256,0,stream>>>(OUTB, WBF+2359296, sa_bo, XW, XW, 512, 512);

  // ---- FFN 2 ----
  ln_kernel<<<4096,256,0,stream>>>(XW, ln5g, ln5b, XN);
  gemm_bt<2><<<dim3(16,128),256,0,stream>>>(XN, WBF+4718592, f2b1, nullptr, HB, 2048, 512);
  gemm_bt<3><<<dim3(4,128),256,0,stream>>>(HB, WBF+5767168, f2b2, XW, (float*)d_out, 512, 2048);
}

// Round 6
// 770.056 us; speedup vs baseline: 1.0918x; 1.0918x over previous
//
// CrossAttentionBlock_56813827392085 — fused transformer block, bf16 MFMA internals. R6:
//  = R4 structure (merged lny/kv/ctx dispatches, fused dinv, fast gelu, colsum-in-softmax)
//  + R3 K-loop (BK=32, 16KB LDS, zero-conflict XOR swizzle, standard MFMA layout).
//  R4's BK=64 cost +27us/GEMM (occupancy drop); R5's transposed epilogue regressed qkv.
#include <hip/hip_runtime.h>
#include <hip/hip_bf16.h>
#include <math.h>
#include <stdint.h>

typedef unsigned short u16;
typedef __attribute__((ext_vector_type(8))) short bh8;
typedef __attribute__((ext_vector_type(4))) float fx4;

#define DEV static __device__ __forceinline__

DEV float bf2f(u16 u){ union{unsigned u; float f;} v; v.u = ((unsigned)u)<<16; return v.f; }
DEV u16 f2bf(float f){ union{float f; unsigned u;} v; v.f = f;
  return (u16)((v.u + 0x7fffu + ((v.u>>16)&1u))>>16); }               // RNE

DEV void async16(const u16* g, u16* l){
  __builtin_amdgcn_global_load_lds((__attribute__((address_space(1))) void*)(uintptr_t)g,
                                   (__attribute__((address_space(3))) void*)l, 16, 0, 0);
}

DEV float gelu_fast(float x){
  float u = 0.7978845608f*(x + 0.044715f*x*x*x);
  float e = __expf(-2.f*fabsf(u));
  float t = __fdividef(1.f - e, 1.f + e);
  t = copysignf(t, u);
  return 0.5f*x*(1.f + t);
}

// ---------------- weight fp32 -> bf16 pack ----------------
struct WDesc { const float* src[14]; int off[14]; };
__global__ __launch_bounds__(256) void convw_kernel(WDesc d, u16* __restrict__ dst){
  int i = blockIdx.x*256 + threadIdx.x;
  int s = 0;
  #pragma unroll
  for(int j=1;j<14;j++) if(i >= d.off[j]) s = j;
  dst[i] = f2bf(d.src[s][i - d.off[s]]);
}

// ---------------- LayerNorm (C=512), fp32 in -> bf16 out ----------------
DEV float wsum64(float s){
  s += __shfl_xor(s,1,64);  s += __shfl_xor(s,2,64);  s += __shfl_xor(s,4,64);
  s += __shfl_xor(s,8,64);  s += __shfl_xor(s,16,64); s += __shfl_xor(s,32,64);
  return s;
}
DEV void ln_row(const float* xrow, const float* g, const float* bta, u16* orow, int lane){
  const float4* xr = (const float4*)xrow + lane*2;
  float4 a = xr[0], c = xr[1];
  float s = a.x+a.y+a.z+a.w + c.x+c.y+c.z+c.w;
  float mean = wsum64(s) * (1.f/512.f);
  float d0=a.x-mean,d1=a.y-mean,d2=a.z-mean,d3=a.w-mean;
  float d4=c.x-mean,d5=c.y-mean,d6=c.z-mean,d7=c.w-mean;
  float sv = d0*d0+d1*d1+d2*d2+d3*d3+d4*d4+d5*d5+d6*d6+d7*d7;
  float rstd = rsqrtf(wsum64(sv)*(1.f/512.f) + 1e-5f);
  const float4* gr = (const float4*)g   + lane*2;
  const float4* br = (const float4*)bta + lane*2;
  float4 g0=gr[0], g1=gr[1], b0=br[0], b1=br[1];
  bh8 o;
  o[0]=(short)f2bf(d0*rstd*g0.x+b0.x); o[1]=(short)f2bf(d1*rstd*g0.y+b0.y);
  o[2]=(short)f2bf(d2*rstd*g0.z+b0.z); o[3]=(short)f2bf(d3*rstd*g0.w+b0.w);
  o[4]=(short)f2bf(d4*rstd*g1.x+b1.x); o[5]=(short)f2bf(d5*rstd*g1.y+b1.y);
  o[6]=(short)f2bf(d6*rstd*g1.z+b1.z); o[7]=(short)f2bf(d7*rstd*g1.w+b1.w);
  *(bh8*)(orow + lane*8) = o;
}
__global__ __launch_bounds__(256) void ln_kernel(const float* __restrict__ x,
    const float* __restrict__ g, const float* __restrict__ bta, u16* __restrict__ out){
  int row  = blockIdx.x*4 + (threadIdx.x>>6);
  ln_row(x + (size_t)row*512, g, bta, out + (size_t)row*512, threadIdx.x&63);
}
__global__ __launch_bounds__(256) void lny_kernel(const float* __restrict__ ys,
    const float* __restrict__ g2, const float* __restrict__ b2, u16* __restrict__ out){
  int row  = blockIdx.x*4 + (threadIdx.x>>6);
  int i = row>>14;
  ln_row(ys + (size_t)row*512, g2 + i*512, b2 + i*512, out + (size_t)row*512, threadIdx.x&63);
}

// ---- shared GEMM K-loop: 128x128 tile, BK=32, swizzled LDS (conflict-free, R3-proven) ----
// C/D layout: out_row = quad*4+r (within 16), out_col = l15.
#define GEMM_KLOOP(Ab, Wb, K)                                                        \
  const int srow = w*32 + (lane>>2);                                                 \
  const int scol = (((lane&3) ^ ((srow>>1)&3)) * 8);                                 \
  const int rsw  = ((l15>>1)&3) ^ quad;                                              \
  for(int k0=0;k0<K;k0+=32){                                                         \
    __syncthreads();                                                                 \
    async16(Ab + (size_t)srow*K      + k0 + scol, &lsA[(w*32   )*32]);               \
    async16(Ab + (size_t)(srow+16)*K + k0 + scol, &lsA[(w*32+16)*32]);               \
    async16(Wb + (size_t)srow*K      + k0 + scol, &lsB[(w*32   )*32]);               \
    async16(Wb + (size_t)(srow+16)*K + k0 + scol, &lsB[(w*32+16)*32]);               \
    __syncthreads();                                                                 \
    bh8 af[4], bfx[4];                                                               \
    _Pragma("unroll")                                                                \
    for(int t=0;t<4;t++){                                                            \
      af[t]  = *(const bh8*)&lsA[(wm*64+t*16+l15)*32 + rsw*8];                       \
      bfx[t] = *(const bh8*)&lsB[(wn*64+t*16+l15)*32 + rsw*8];                       \
    }                                                                                \
    _Pragma("unroll")                                                                \
    for(int mt=0;mt<4;mt++)                                                          \
      _Pragma("unroll")                                                              \
      for(int nt=0;nt<4;nt++)                                                        \
        acc[mt][nt] = __builtin_amdgcn_mfma_f32_16x16x32_bf16(af[mt], bfx[nt], acc[mt][nt], 0,0,0); \
  }

// ---------------- multi-output projection GEMM: C_sub = A * W_sub^T + bias ----------------
// Input-set index i = bm>>7 selects W/bias/ksum offsets (merged CA kv: grid y=256).
struct SubD { const float* bias; u16* out; float* ksum; int mode; };
struct Subs3 { SubD s[3]; };
__global__ __launch_bounds__(256) void gemm_qkv(const u16* __restrict__ A,
    const u16* __restrict__ W, Subs3 subs, int K, int wstride, int bstride, int ksstride){
  __shared__ __align__(16) u16 lsA[128*32];
  __shared__ __align__(16) u16 lsB[128*32];
  const int tid = threadIdx.x, lane = tid&63, w = tid>>6;
  const int quad = lane>>4, l15 = lane&15;
  const int bn = blockIdx.x, bm = blockIdx.y;
  const int iset = bm>>7;
  const int wm = w&1, wn = w>>1;
  fx4 acc[4][4];
  #pragma unroll
  for(int i=0;i<4;i++)
    #pragma unroll
    for(int j=0;j<4;j++) acc[i][j] = (fx4){0.f,0.f,0.f,0.f};
  const u16* Ab = A + (size_t)bm*128*K;
  const u16* Wb = W + (size_t)iset*wstride + (size_t)bn*128*K;
  GEMM_KLOOP(Ab, Wb, K)
  const SubD sub = subs.s[bn>>2];
  const int colw = (bn&3)*128 + wn*64;
  const float* bias = sub.bias + iset*bstride;
  float bcol[4];
  #pragma unroll
  for(int nt=0;nt<4;nt++) bcol[nt] = bias[colw + nt*16 + l15];

  if(sub.mode==1){
    float ksacc[4] = {0.f,0.f,0.f,0.f};
    #pragma unroll
    for(int mt=0;mt<4;mt++)
      #pragma unroll
      for(int r=0;r<4;r++){
        float v0=acc[mt][0][r]+bcol[0], v1=acc[mt][1][r]+bcol[1];
        float v2=acc[mt][2][r]+bcol[2], v3=acc[mt][3][r]+bcol[3];
        float mx = fmaxf(fmaxf(v0,v1),fmaxf(v2,v3));
        mx = fmaxf(mx,__shfl_xor(mx,1,64)); mx = fmaxf(mx,__shfl_xor(mx,2,64));
        mx = fmaxf(mx,__shfl_xor(mx,4,64)); mx = fmaxf(mx,__shfl_xor(mx,8,64));
        float e0=__expf(v0-mx), e1=__expf(v1-mx), e2=__expf(v2-mx), e3=__expf(v3-mx);
        float s = e0+e1+e2+e3;
        s += __shfl_xor(s,1,64); s += __shfl_xor(s,2,64);
        s += __shfl_xor(s,4,64); s += __shfl_xor(s,8,64);
        float inv = __fdividef(1.f, s);
        e0*=inv; e1*=inv; e2*=inv; e3*=inv;
        ksacc[0]+=e0; ksacc[1]+=e1; ksacc[2]+=e2; ksacc[3]+=e3;
        int row = bm*128 + wm*64 + mt*16 + quad*4 + r;
        size_t rb = (size_t)row*512;
        sub.out[rb+colw+ 0+l15]=f2bf(e0); sub.out[rb+colw+16+l15]=f2bf(e1);
        sub.out[rb+colw+32+l15]=f2bf(e2); sub.out[rb+colw+48+l15]=f2bf(e3);
      }
    if(sub.ksum){
      int b = (bm&127)>>5;
      float* ks = sub.ksum + iset*ksstride + b*512;
      #pragma unroll
      for(int nt=0;nt<4;nt++){
        float s = ksacc[nt];
        s += __shfl_xor(s,16,64); s += __shfl_xor(s,32,64);
        if(quad==0) atomicAdd(&ks[colw + nt*16 + l15], s);
      }
    }
  } else {
    #pragma unroll
    for(int mt=0;mt<4;mt++)
      #pragma unroll
      for(int r=0;r<4;r++){
        int row = bm*128 + wm*64 + mt*16 + quad*4 + r;
        size_t rb = (size_t)row*512;
        #pragma unroll
        for(int nt=0;nt<4;nt++)
          sub.out[rb + colw + nt*16 + l15] = f2bf(acc[mt][nt][r] + bcol[nt]);
      }
  }
}

// ---------------- GEMM C = A[MxK] * W[NxK]^T + bias, EPI 2: gelu->bf16, 3: +res->fp32 ----
template<int EPI>
__global__ __launch_bounds__(256) void gemm_bt(const u16* __restrict__ A,
    const u16* __restrict__ W, const float* __restrict__ bias,
    const float* __restrict__ res, void* __restrict__ out, int N, int K){
  __shared__ __align__(16) u16 lsA[128*32];
  __shared__ __align__(16) u16 lsB[128*32];
  const int tid = threadIdx.x, lane = tid&63, w = tid>>6;
  const int quad = lane>>4, l15 = lane&15;
  const int bn = blockIdx.x, bm = blockIdx.y;
  const int wm = w&1, wn = w>>1;
  fx4 acc[4][4];
  #pragma unroll
  for(int i=0;i<4;i++)
    #pragma unroll
    for(int j=0;j<4;j++) acc[i][j] = (fx4){0.f,0.f,0.f,0.f};
  const u16* Ab = A + (size_t)bm*128*K;
  const u16* Wb = W + (size_t)bn*128*K;
  GEMM_KLOOP(Ab, Wb, K)
  const int colbase = bn*128 + wn*64;
  float bcol[4];
  #pragma unroll
  for(int nt=0;nt<4;nt++) bcol[nt] = bias[colbase + nt*16 + l15];

  if(EPI==3){
    float* of = (float*)out;
    #pragma unroll
    for(int mt=0;mt<4;mt++)
      #pragma unroll
      for(int r=0;r<4;r++){
        int row = bm*128 + wm*64 + mt*16 + quad*4 + r;
        size_t rb = (size_t)row*N;
        #pragma unroll
        for(int nt=0;nt<4;nt++){
          int col = colbase + nt*16 + l15;
          of[rb+col] = res[rb+col] + acc[mt][nt][r] + bcol[nt];
        }
      }
  } else {
    u16* ob = (u16*)out;
    #pragma unroll
    for(int mt=0;mt<4;mt++)
      #pragma unroll
      for(int r=0;r<4;r++){
        int row = bm*128 + wm*64 + mt*16 + quad*4 + r;
        size_t rb = (size_t)row*N;
        #pragma unroll
        for(int nt=0;nt<4;nt++)
          ob[rb + colbase + nt*16 + l15] = f2bf(gelu_fast(acc[mt][nt][r] + bcol[nt]));
      }
  }
}

// ---------------- ctx[i,b,h][d1][d2] = sum_t k[t][d1] v[t][d2] (MFMA over t) ----------------
__global__ __launch_bounds__(256) void ctx_kernel(const u16* __restrict__ kb,
    const u16* __restrict__ vb, float* __restrict__ ctx, size_t kstride){
  __shared__ __align__(16) u16 lk[64*72];  // transposed [d][t], stride 72
  __shared__ __align__(16) u16 lv[64*72];
  const int tid=threadIdx.x, lane=tid&63, w=tid>>6, quad=lane>>4, l15=lane&15;
  const int bh2 = blockIdx.x, i = bh2>>5, h = bh2&7, b = (bh2>>3)&3;
  const u16* kbase = kb + (size_t)i*kstride;
  const u16* vbase = vb + (size_t)i*kstride;
  const size_t rowbase = (size_t)b*4096 + (size_t)blockIdx.y*512;
  const int mt0=(w&1)*32, nt0=(w>>1)*32;
  fx4 acc[2][2];
  #pragma unroll
  for(int x=0;x<2;x++)
    #pragma unroll
    for(int j=0;j<2;j++) acc[x][j] = (fx4){0.f,0.f,0.f,0.f};
  const int tl = tid>>2, part = tid&3;
  for(int it=0; it<8; it++){
    __syncthreads();
    {
      size_t gro = (rowbase + it*64 + tl)*512 + h*64 + part*16;
      bh8 k0 = *(const bh8*)(kbase + gro); bh8 k1 = *(const bh8*)(kbase + gro + 8);
      bh8 v0 = *(const bh8*)(vbase + gro); bh8 v1 = *(const bh8*)(vbase + gro + 8);
      #pragma unroll
      for(int j=0;j<8;j++){
        lk[(part*16+j  )*72 + tl] = (u16)k0[j];
        lk[(part*16+8+j)*72 + tl] = (u16)k1[j];
        lv[(part*16+j  )*72 + tl] = (u16)v0[j];
        lv[(part*16+8+j)*72 + tl] = (u16)v1[j];
      }
    }
    __syncthreads();
    #pragma unroll
    for(int ks=0;ks<2;ks++){
      bh8 a0 = *(const bh8*)&lk[(mt0    +l15)*72 + ks*32 + quad*8];
      bh8 a1 = *(const bh8*)&lk[(mt0+16 +l15)*72 + ks*32 + quad*8];
      bh8 b0 = *(const bh8*)&lv[(nt0    +l15)*72 + ks*32 + quad*8];
      bh8 b1 = *(const bh8*)&lv[(nt0+16 +l15)*72 + ks*32 + quad*8];
      acc[0][0] = __builtin_amdgcn_mfma_f32_16x16x32_bf16(a0,b0,acc[0][0],0,0,0);
      acc[0][1] = __builtin_amdgcn_mfma_f32_16x16x32_bf16(a0,b1,acc[0][1],0,0,0);
      acc[1][0] = __builtin_amdgcn_mfma_f32_16x16x32_bf16(a1,b0,acc[1][0],0,0,0);
      acc[1][1] = __builtin_amdgcn_mfma_f32_16x16x32_bf16(a1,b1,acc[1][1],0,0,0);
    }
  }
  float* cb = ctx + (size_t)bh2*4096;
  #pragma unroll
  for(int mi=0;mi<2;mi++)
    #pragma unroll
    for(int ni=0;ni<2;ni++)
      #pragma unroll
      for(int r=0;r<4;r++){
        int d1 = mt0 + mi*16 + quad*4 + r;
        int d2 = nt0 + ni*16 + l15;
        atomicAdd(&cb[d1*64 + d2], acc[mi][ni][r]);
      }
}

// ------- out = q + sum_i (q @ ctx_i) * Dinv_i, Dinv fused (quad-shuffle over q frags) -------
template<int NIN>
__global__ __launch_bounds__(256) void apply_kernel(const u16* __restrict__ q,
    const float* __restrict__ ctx, const float* __restrict__ ksum, float eps,
    u16* __restrict__ out){
  __shared__ __align__(16) u16 lctx[(NIN+1)*64*72];
  const int tid=threadIdx.x, lane=tid&63, w=tid>>6, quad=lane>>4, l15=lane&15;
  const int bh = blockIdx.x, b=bh>>3, h=bh&7;
  {
    int base = tid*16;
    int d1 = base>>6, d2b = base&63;
    #pragma unroll
    for(int s=0;s<=NIN;s++){
      u16* dst = &lctx[s*64*72];
      if(s<NIN){
        const float* sp = ctx + ((size_t)s*32 + bh)*4096 + base;
        #pragma unroll
        for(int j=0;j<16;j++) dst[(d2b+j)*72 + d1] = f2bf(sp[j]);
      } else {
        #pragma unroll
        for(int j=0;j<16;j++) dst[(d2b+j)*72 + d1] = ((d2b+j)==d1) ? (u16)0x3f80 : (u16)0;
      }
    }
  }
  float kslo[NIN][8], kshi[NIN][8];
  #pragma unroll
  for(int s=0;s<NIN;s++){
    const float* ks = ksum + s*2048 + b*512 + h*64;
    #pragma unroll
    for(int j=0;j<8;j++){ kslo[s][j] = ks[quad*8+j]; kshi[s][j] = ks[32+quad*8+j]; }
  }
  __syncthreads();
  bh8 bfr[NIN+1][4][2];
  #pragma unroll
  for(int s=0;s<=NIN;s++)
    #pragma unroll
    for(int nt=0;nt<4;nt++)
      #pragma unroll
      for(int ks=0;ks<2;ks++)
        bfr[s][nt][ks] = *(const bh8*)&lctx[s*64*72 + (nt*16+l15)*72 + ks*32 + quad*8];
  const size_t tb0 = (size_t)b*4096 + (size_t)blockIdx.y*256 + w*64;
  for(int g=0;g<4;g++){
    size_t tb = tb0 + g*16;
    const u16* qr = q + (tb + l15)*512 + h*64;
    bh8 a0 = *(const bh8*)(qr + quad*8);
    bh8 a1 = *(const bh8*)(qr + 32 + quad*8);
    float dv[NIN][4];
    #pragma unroll
    for(int s=0;s<NIN;s++){
      float part = 0.f;
      #pragma unroll
      for(int j=0;j<8;j++)
        part += bf2f((u16)a0[j])*kslo[s][j] + bf2f((u16)a1[j])*kshi[s][j];
      part += __shfl_xor(part,16,64); part += __shfl_xor(part,32,64);
      #pragma unroll
      for(int r=0;r<4;r++)
        dv[s][r] = __fdividef(1.f, __shfl(part, quad*4+r, 64) + eps);
    }
    fx4 outv[4];
    #pragma unroll
    for(int nt=0;nt<4;nt++) outv[nt] = (fx4){0.f,0.f,0.f,0.f};
    #pragma unroll
    for(int s=0;s<=NIN;s++){
      fx4 c[4];
      #pragma unroll
      for(int nt=0;nt<4;nt++){
        c[nt] = (fx4){0.f,0.f,0.f,0.f};
        c[nt] = __builtin_amdgcn_mfma_f32_16x16x32_bf16(a0, bfr[s][nt][0], c[nt], 0,0,0);
        c[nt] = __builtin_amdgcn_mfma_f32_16x16x32_bf16(a1, bfr[s][nt][1], c[nt], 0,0,0);
      }
      #pragma unroll
      for(int nt=0;nt<4;nt++)
        #pragma unroll
        for(int r=0;r<4;r++) outv[nt][r] += c[nt][r]*((s==NIN)?1.f:dv[s][r]);
    }
    #pragma unroll
    for(int nt=0;nt<4;nt++)
      #pragma unroll
      for(int r=0;r<4;r++)
        out[(tb+quad*4+r)*512 + h*64 + nt*16 + l15] = f2bf(outv[nt][r]);
  }
}

// =========================================================================
extern "C" void kernel_launch(void* const* d_in, const int* in_sizes, int n_in,
                              void* d_out, int out_size, void* d_ws, size_t ws_size,
                              hipStream_t stream){
  const float* x_in =(const float*)d_in[0];
  const float* ys   =(const float*)d_in[1];
  const float* ln1g =(const float*)d_in[2],  *ln1b=(const float*)d_in[3];
  const float* ln2g =(const float*)d_in[4],  *ln2b=(const float*)d_in[5];
  const float* ln3g =(const float*)d_in[6],  *ln3b=(const float*)d_in[7];
  const float* ln4g =(const float*)d_in[8],  *ln4b=(const float*)d_in[9];
  const float* ln5g =(const float*)d_in[10], *ln5b=(const float*)d_in[11];
  const float* ca_wq=(const float*)d_in[12], *ca_bq=(const float*)d_in[13];
  const float* ca_wk=(const float*)d_in[14], *ca_bk=(const float*)d_in[15];
  const float* ca_wv=(const float*)d_in[16], *ca_bv=(const float*)d_in[17];
  const float* ca_wo=(const float*)d_in[18], *ca_bo=(const float*)d_in[19];
  const float* sa_wq=(const float*)d_in[20], *sa_bq=(const float*)d_in[21];
  const float* sa_wk=(const float*)d_in[22], *sa_bk=(const float*)d_in[23];
  const float* sa_wv=(const float*)d_in[24], *sa_bv=(const float*)d_in[25];
  const float* sa_wo=(const float*)d_in[26], *sa_bo=(const float*)d_in[27];
  const float* f1w1 =(const float*)d_in[28], *f1b1=(const float*)d_in[29];
  const float* f1w2 =(const float*)d_in[30], *f1b2=(const float*)d_in[31];
  const float* f2w1 =(const float*)d_in[32], *f2b1=(const float*)d_in[33];
  const float* f2w2 =(const float*)d_in[34], *f2b2=(const float*)d_in[35];

  char* p = (char*)d_ws;
  u16*   WBF = (u16*)p;    p += 13631488;   // bf16 weights
  float* XW  = (float*)p;  p += 33554432;   // residual stream fp32 [16384,512]
  u16*   XN2 = (u16*)p;    p += 33554432;   // LN out, up to 2x16384 rows
  u16*   QB  = (u16*)p;    p += 16777216;
  u16*   R1  = (u16*)p;    p += 67108864;   // FFN hidden [16384,2048] OR stacked KB2|VB2
  u16*   OUTB= (u16*)p;    p += 16777216;   // attention output
  float* SM  = (float*)p;  p += 1597440;    // ctx + ksum (zeroed)
  u16*   XN  = XN2;
  u16*   KB2 = R1;
  u16*   VB2 = R1 + 16777216;
  u16*   HB  = R1;
  float* CTXC = SM;                          // [2][32][4096]
  float* CTXS = SM + 262144;                 // [32][4096]
  float* KSC  = SM + 393216;                 // [2][4][512]
  float* KSS  = SM + 397312;                 // [4][512]

  WDesc wd;
  const float* wsrc[14] = {ca_wq, ca_wk, ca_wv, ca_wk+262144, ca_wv+262144, ca_wo,
                           sa_wq, sa_wk, sa_wv, sa_wo, f1w1, f1w2, f2w1, f2w2};
  const int    woff[14] = {0, 262144, 524288, 786432, 1048576, 1310720,
                           1572864, 1835008, 2097152, 2359296,
                           2621440, 3670016, 4718592, 5767168};
  for(int i=0;i<14;i++){ wd.src[i]=wsrc[i]; wd.off[i]=woff[i]; }
  convw_kernel<<<26624,256,0,stream>>>(wd, WBF);
  hipMemsetAsync(SM, 0, 399360*sizeof(float), stream);

  SubD zsub = {nullptr,nullptr,nullptr,0};

  // ---- cross attention ----
  ln_kernel<<<4096,256,0,stream>>>(x_in, ln1g, ln1b, XN);
  { Subs3 s = {{ {ca_bq, QB, nullptr, 1}, zsub, zsub }};
    gemm_qkv<<<dim3(4,128),256,0,stream>>>(XN, WBF+0, s, 512, 0,0,0); }
  lny_kernel<<<8192,256,0,stream>>>(ys, ln2g, ln2b, XN2);   // both ys LNs
  { Subs3 s = {{ {ca_bk, KB2, KSC, 1}, {ca_bv, VB2, nullptr, 0}, zsub }};
    gemm_qkv<<<dim3(8,256),256,0,stream>>>(XN2, WBF+262144, s, 512,
                                           524288, 512, 2048); }  // i = bm>>7
  ctx_kernel<<<dim3(64,8),256,0,stream>>>(KB2, VB2, CTXC, (size_t)16384*512);
  apply_kernel<2><<<dim3(32,16),256,0,stream>>>(QB, CTXC, KSC, 1e-8f, OUTB);
  gemm_bt<3><<<dim3(4,128),256,0,stream>>>(OUTB, WBF+1310720, ca_bo, x_in, XW, 512, 512);

  // ---- FFN 1 ----
  ln_kernel<<<4096,256,0,stream>>>(XW, ln3g, ln3b, XN);
  gemm_bt<2><<<dim3(16,128),256,0,stream>>>(XN, WBF+2621440, f1b1, nullptr, HB, 2048, 512);
  gemm_bt<3><<<dim3(4,128),256,0,stream>>>(HB, WBF+3670016, f1b2, XW, XW, 512, 2048);

  // ---- linear self attention ----
  ln_kernel<<<4096,256,0,stream>>>(XW, ln4g, ln4b, XN);
  { Subs3 s = {{ {sa_bq, QB, nullptr, 1}, {sa_bk, KB2, KSS, 1}, {sa_bv, VB2, nullptr, 0} }};
    gemm_qkv<<<dim3(12,128),256,0,stream>>>(XN, WBF+1572864, s, 512, 0,0,0); }
  ctx_kernel<<<dim3(32,8),256,0,stream>>>(KB2, VB2, CTXS, 0);
  apply_kernel<1><<<dim3(32,16),256,0,stream>>>(QB, CTXS, KSS, 0.f, OUTB);
  gemm_bt<3><<<dim3(4,128),256,0,stream>>>(OUTB, WBF+2359296, sa_bo, XW, XW, 512, 512);

  // ---- FFN 2 ----
  ln_kernel<<<4096,256,0,stream>>>(XW, ln5g, ln5b, XN);
  gemm_bt<2><<<dim3(16,128),256,0,stream>>>(XN, WBF+4718592, f2b1, nullptr, HB, 2048, 512);
  gemm_bt<3><<<dim3(4,128),256,0,stream>>>(HB, WBF+5767168, f2b2, XW, (float*)d_out, 512, 2048);
}